// Round 5
// baseline (155.653 us; speedup 1.0000x reference)
//
#include <hip/hip_runtime.h>
#include <hip/hip_bf16.h>
#include <stdint.h>

#define T_SEQ 1024
#define C_DIM 1024
#define NH 16
#define DH 64

typedef __attribute__((ext_vector_type(8))) __bf16 bf16x8;
typedef __attribute__((ext_vector_type(8))) uint16_t u16x8;
typedef __attribute__((ext_vector_type(4))) float f32x4;

__device__ __forceinline__ uint16_t f2bf(float f) {
    union { float f; uint32_t u; } v; v.f = f;
    uint32_t u = v.u;
    return (uint16_t)((u + 0x7FFFu + ((u >> 16) & 1u)) >> 16);
}
__device__ __forceinline__ float bf2f(uint16_t b) {
    union { uint32_t u; float f; } v; v.u = ((uint32_t)b) << 16; return v.f;
}

// ---------- cast x f32 -> bf16 (vectorized) ----------
__global__ void k_cast(const float* __restrict__ in, uint16_t* __restrict__ out, int n4) {
    int i = blockIdx.x * blockDim.x + threadIdx.x;
    int st = gridDim.x * blockDim.x;
    for (; i < n4; i += st) {
        float4 v = reinterpret_cast<const float4*>(in)[i];
        ushort4 o;
        o.x = f2bf(v.x); o.y = f2bf(v.y); o.z = f2bf(v.z); o.w = f2bf(v.w);
        reinterpret_cast<ushort4*>(out)[i] = o;
    }
}

// ---------- fused transpose+cast of all 4 weights: W[k][n] f32 -> Wt[n][k] bf16 ----------
__global__ void k_transpose4(const float* __restrict__ W0, const float* __restrict__ W1,
                             const float* __restrict__ W2, const float* __restrict__ W3,
                             uint16_t* __restrict__ out) {
    __shared__ float tile[32][33];
    const float* in = (blockIdx.z == 0) ? W0 : (blockIdx.z == 1) ? W1 : (blockIdx.z == 2) ? W2 : W3;
    uint16_t* o = out + ((size_t)blockIdx.z << 20);
    int bx = blockIdx.x * 32;  // n block
    int by = blockIdx.y * 32;  // k block
    int tx = threadIdx.x, ty = threadIdx.y;
#pragma unroll
    for (int i = 0; i < 4; i++)
        tile[ty + i * 8][tx] = in[(size_t)(by + ty + i * 8) * C_DIM + bx + tx];
    __syncthreads();
#pragma unroll
    for (int i = 0; i < 4; i++)
        o[(size_t)(bx + ty + i * 8) * C_DIM + by + tx] = f2bf(tile[tx][ty + i * 8]);
}

// ---------- V column mean (uniform-softmax fallback for fully-masked rows) ----------
__global__ void k_vmean(const uint16_t* __restrict__ Vt, float* __restrict__ Vmean) {
    const int bh = blockIdx.x;           // 64
    const int tid = threadIdx.x;         // 256
    const int d = tid >> 2, part = tid & 3;
    const uint16_t* src = Vt + ((size_t)bh * DH + d) * T_SEQ + part * 256;
    float s = 0.f;
#pragma unroll
    for (int i = 0; i < 32; i++) {
        u16x8 v = *reinterpret_cast<const u16x8*>(src + i * 8);
#pragma unroll
        for (int j = 0; j < 8; j++) s += bf2f(v[j]);
    }
    s += __shfl_xor(s, 1);
    s += __shfl_xor(s, 2);
    if (part == 0) Vmean[bh * DH + d] = s * (1.0f / 1024.0f);
}

// ---------- shared GEMM staging: one 128x32 A tile + 128x32 B tile ----------
__device__ __forceinline__ void stage_g(const uint16_t* A, const uint16_t* Bt, int bm, int bn,
                                        int kt, char* la, char* lb, int tid) {
    const int w = tid >> 6, srow = tid >> 2, scol = (tid & 3) * 8;
#pragma unroll
    for (int p = 0; p < 2; p++) {
        const uint16_t* ga = A + (size_t)(bm + p * 64 + srow) * C_DIM + kt + scol;
        const uint16_t* gb = Bt + (size_t)(bn + p * 64 + srow) * C_DIM + kt + scol;
        __builtin_amdgcn_global_load_lds(
            (const __attribute__((address_space(1))) void*)ga,
            (__attribute__((address_space(3))) void*)(la + p * 4096 + w * 1024), 16, 0, 0);
        __builtin_amdgcn_global_load_lds(
            (const __attribute__((address_space(1))) void*)gb,
            (__attribute__((address_space(3))) void*)(lb + p * 4096 + w * 1024), 16, 0, 0);
    }
}

// ---------- fused QKV GEMM: [4096][1024] x [3072][1024]^T, 2-phase dbuf ----------
__global__ __launch_bounds__(256) void k_gemm_qkv(const uint16_t* __restrict__ A,
                                                  const uint16_t* __restrict__ Bt,
                                                  const float* __restrict__ bq,
                                                  const float* __restrict__ bk,
                                                  const float* __restrict__ bv,
                                                  uint16_t* __restrict__ qb,
                                                  uint16_t* __restrict__ kb,
                                                  uint16_t* __restrict__ vt) {
    __shared__ uint16_t lA[2][128 * 32];
    __shared__ uint16_t lB[2][128 * 32];
    const int bm = blockIdx.x * 128;
    const int bn = blockIdx.y * 128;
    const int tid = threadIdx.x;
    const int lane = tid & 63;
    const int w = tid >> 6;
    const int wm = (w >> 1) * 64;
    const int wn = (w & 1) * 64;
    const int ko = (lane >> 4) * 8;
    const int rr = lane & 15;

    f32x4 acc[4][4] = {};

    stage_g(A, Bt, bm, bn, 0, (char*)lA[0], (char*)lB[0], tid);
    __syncthreads();
    for (int t = 0; t < 32; t++) {
        const int c = t & 1;
        if (t < 31) stage_g(A, Bt, bm, bn, (t + 1) * 32, (char*)lA[c ^ 1], (char*)lB[c ^ 1], tid);
        bf16x8 af[4], bfr[4];
#pragma unroll
        for (int i = 0; i < 4; i++) {
            af[i]  = *reinterpret_cast<const bf16x8*>(&lA[c][(wm + i * 16 + rr) * 32 + ko]);
            bfr[i] = *reinterpret_cast<const bf16x8*>(&lB[c][(wn + i * 16 + rr) * 32 + ko]);
        }
#pragma unroll
        for (int mi = 0; mi < 4; mi++)
#pragma unroll
            for (int ni = 0; ni < 4; ni++)
                acc[mi][ni] = __builtin_amdgcn_mfma_f32_16x16x32_bf16(af[mi], bfr[ni], acc[mi][ni], 0, 0, 0);
        __syncthreads();   // drains t+1 stage; orders buf reads before next overwrite
    }

    const float* bias; uint16_t* outp; int coff, vmode;
    if (bn < 1024)      { bias = bq; outp = qb; coff = 0;    vmode = 0; }
    else if (bn < 2048) { bias = bk; outp = kb; coff = 1024; vmode = 0; }
    else                { bias = bv; outp = vt; coff = 2048; vmode = 1; }

    const int r0 = (lane >> 4) * 4;
    const int cc = lane & 15;
#pragma unroll
    for (int ni = 0; ni < 4; ni++) {
        const int colg = bn + wn + ni * 16 + cc;
        const int col = colg - coff;
        const float bvv = bias[col];
#pragma unroll
        for (int mi = 0; mi < 4; mi++) {
#pragma unroll
            for (int jj = 0; jj < 4; jj++) {
                const int row = bm + wm + mi * 16 + r0 + jj;
                float v = acc[mi][ni][jj] + bvv;
                if (vmode == 0) {
                    outp[(size_t)row * C_DIM + col] = f2bf(v);
                } else {
                    const int b = row >> 10, t2 = row & 1023;
                    const int h = col >> 6, d = col & 63;
                    outp[((size_t)((b * NH + h) * DH + d) << 10) + t2] = f2bf(v);
                }
            }
        }
    }
}

// ---------- output-proj GEMM: f32 out, 2-phase dbuf ----------
__global__ __launch_bounds__(256) void k_gemm_o(const uint16_t* __restrict__ A,
                                                const uint16_t* __restrict__ Bt,
                                                const float* __restrict__ bias,
                                                float* __restrict__ Out) {
    __shared__ uint16_t lA[2][128 * 32];
    __shared__ uint16_t lB[2][128 * 32];
    const int bm = blockIdx.x * 128;
    const int bn = blockIdx.y * 128;
    const int tid = threadIdx.x;
    const int lane = tid & 63;
    const int w = tid >> 6;
    const int wm = (w >> 1) * 64;
    const int wn = (w & 1) * 64;
    const int ko = (lane >> 4) * 8;
    const int rr = lane & 15;

    f32x4 acc[4][4] = {};

    stage_g(A, Bt, bm, bn, 0, (char*)lA[0], (char*)lB[0], tid);
    __syncthreads();
    for (int t = 0; t < 32; t++) {
        const int c = t & 1;
        if (t < 31) stage_g(A, Bt, bm, bn, (t + 1) * 32, (char*)lA[c ^ 1], (char*)lB[c ^ 1], tid);
        bf16x8 af[4], bfr[4];
#pragma unroll
        for (int i = 0; i < 4; i++) {
            af[i]  = *reinterpret_cast<const bf16x8*>(&lA[c][(wm + i * 16 + rr) * 32 + ko]);
            bfr[i] = *reinterpret_cast<const bf16x8*>(&lB[c][(wn + i * 16 + rr) * 32 + ko]);
        }
#pragma unroll
        for (int mi = 0; mi < 4; mi++)
#pragma unroll
            for (int ni = 0; ni < 4; ni++)
                acc[mi][ni] = __builtin_amdgcn_mfma_f32_16x16x32_bf16(af[mi], bfr[ni], acc[mi][ni], 0, 0, 0);
        __syncthreads();
    }

    const int r0 = (lane >> 4) * 4;
    const int cc = lane & 15;
#pragma unroll
    for (int ni = 0; ni < 4; ni++) {
        const int col = bn + wn + ni * 16 + cc;
        const float bvv = bias[col];
#pragma unroll
        for (int mi = 0; mi < 4; mi++)
#pragma unroll
            for (int jj = 0; jj < 4; jj++) {
                const int row = bm + wm + mi * 16 + r0 + jj;
                Out[(size_t)row * C_DIM + col] = acc[mi][ni][jj] + bvv;
            }
    }
}

// Stage one 64x64 bf16 K tile (8KB) into LDS, linear dest + inverse-swizzled source.
__device__ __forceinline__ void stage_k(const uint16_t* kbase, int s0, char* buf, int tid) {
    const int w = tid >> 6;
    const int cb = (((tid & 7) ^ ((tid >> 3) & 7)) << 4);
#pragma unroll
    for (int i = 0; i < 2; i++) {
        const int r = i * 32 + (tid >> 3);
        const uint16_t* src = kbase + (size_t)(s0 + r) * C_DIM + (cb >> 1);
        __builtin_amdgcn_global_load_lds(
            (const __attribute__((address_space(1))) void*)src,
            (__attribute__((address_space(3))) void*)(buf + i * 4096 + w * 1024), 16, 0, 0);
    }
}

// ---------- flash attention: m=0 softmax (no online max), deferred l-reduce ----------
// 4-wave block, 64 q-rows, LDS-staged K (dbuf+swizzle), V direct global->reg.
// Fully-masked rows (row 1023 only) get l==0 -> uniform fallback via Vmean.
__global__ __launch_bounds__(256, 4) void k_attn(const uint16_t* __restrict__ Q,
                                                 const uint16_t* __restrict__ Kb,
                                                 const uint16_t* __restrict__ Vt,
                                                 const float* __restrict__ Vmean,
                                                 uint16_t* __restrict__ Ob) {
    __shared__ char smem[16384 + 4 * 2304];  // K dbuf 2x8KB + P 4x(16x72x2B)
    const int tid = threadIdx.x;
    const int lane = tid & 63;
    const int w = tid >> 6;
    uint16_t* lp = reinterpret_cast<uint16_t*>(smem + 16384 + w * 2304);

    // XCD swizzle (bijective): 8 heads per XCD; zigzag qblk for load balance
    const int id = blockIdx.x;
    const int sw = (id & 7) * 128 + (id >> 3);
    const int bh = sw >> 4;
    const int jj = sw & 15;
    const int qblk = (jj & 1) ? (15 - (jj >> 1)) : (jj >> 1);
    const int q0 = qblk * 64;
    const int bb = bh >> 4, h = bh & 15;
    const int qq = lane & 15;
    const int g  = lane >> 4;
    const int ko = g * 8;
    const int r0 = g * 4;
    const int qg = q0 + w * 16 + qq;

    const uint16_t* qp = Q + (size_t)(bb * T_SEQ + qg) * C_DIM + h * DH + ko;
    bf16x8 bq0 = *reinterpret_cast<const bf16x8*>(qp);
    bf16x8 bq1 = *reinterpret_cast<const bf16x8*>(qp + 32);

    const uint16_t* kbase = Kb + (size_t)bb * T_SEQ * C_DIM + h * DH;
    const uint16_t* vbase = Vt + (size_t)bh * DH * T_SEQ;

    f32x4 o[4] = {};
    float ll = 0.f;                              // per-lane partial row-sum of P
    const float zs = 0.125f * 1.44269504088896f;

    // tiles with s0+63 <= q0 contribute exactly 0 (mask underflow) -> skip.
    // qblk==15 also starts at its own tile; row 1023 handled by Vmean fallback.
    const int t0 = qblk;
    stage_k(kbase, t0 * 64, smem, tid);

    const int swz0 = ((g * 16) ^ ((qq & 7) << 4)) >> 1;        // elem off, cols 0-31
    const int swz1 = ((64 + g * 16) ^ ((qq & 7) << 4)) >> 1;   // elem off, cols 32-63

    for (int t = t0; t < 16; t++) {
        const int cur = (t - t0) & 1;
        __syncthreads();   // K(t) landed; buf[cur^1] free
        if (t < 15) stage_k(kbase, (t + 1) * 64, smem + (cur ^ 1) * 8192, tid);
        const int s0 = t * 64;

        // V direct loads, issued early; latency hides under QK+softmax
        bf16x8 vf[4][2];
#pragma unroll
        for (int ni = 0; ni < 4; ni++) {
            const uint16_t* vp = vbase + (size_t)(ni * 16 + qq) * T_SEQ + s0 + ko;
            vf[ni][0] = *reinterpret_cast<const bf16x8*>(vp);
            vf[ni][1] = *reinterpret_cast<const bf16x8*>(vp + 32);
        }

        const uint16_t* kb_cur = reinterpret_cast<const uint16_t*>(smem + cur * 8192);
        f32x4 sc[4];
#pragma unroll
        for (int hf = 0; hf < 4; hf++) {
            const int rb = (hf * 16 + qq) * 64;
            bf16x8 k0 = *reinterpret_cast<const bf16x8*>(&kb_cur[rb + swz0]);
            bf16x8 k1 = *reinterpret_cast<const bf16x8*>(&kb_cur[rb + swz1]);
            f32x4 tt = {};
            tt = __builtin_amdgcn_mfma_f32_16x16x32_bf16(k0, bq0, tt, 0, 0, 0);
            tt = __builtin_amdgcn_mfma_f32_16x16x32_bf16(k1, bq1, tt, 0, 0, 0);
            sc[hf] = tt;   // sc[hf][j] = S[k=s0+hf*16+r0+j][q=qg]
        }
        // m=0 softmax: P = exp2(z), masked z -> -1e9 -> P = 0 exactly
#pragma unroll
        for (int hf = 0; hf < 4; hf++)
#pragma unroll
            for (int j = 0; j < 4; j++) {
                const int k = s0 + hf * 16 + r0 + j;
                const float z = sc[hf][j] * zs + ((k <= qg) ? -1e9f : 0.0f);
                const float p = __builtin_amdgcn_exp2f(z);
                sc[hf][j] = p;
                ll += p;
            }
        // pack P -> per-wave LDS (lp[q][k], stride 72) — wave-private
        uint32_t* lp32 = reinterpret_cast<uint32_t*>(lp);
#pragma unroll
        for (int hf = 0; hf < 4; hf++)
#pragma unroll
            for (int jp = 0; jp < 2; jp++) {
                union { __hip_bfloat162 h2; uint32_t u; } cv;
                cv.h2 = __float22bfloat162_rn(make_float2(sc[hf][2 * jp], sc[hf][2 * jp + 1]));
                lp32[qq * 36 + hf * 8 + (r0 >> 1) + jp] = cv.u;
            }
        bf16x8 pa0 = *reinterpret_cast<const bf16x8*>(&lp[qq * 72 + ko]);
        bf16x8 pa1 = *reinterpret_cast<const bf16x8*>(&lp[qq * 72 + 32 + ko]);
#pragma unroll
        for (int ni = 0; ni < 4; ni++) {
            o[ni] = __builtin_amdgcn_mfma_f32_16x16x32_bf16(pa0, vf[ni][0], o[ni], 0, 0, 0);
            o[ni] = __builtin_amdgcn_mfma_f32_16x16x32_bf16(pa1, vf[ni][1], o[ni], 0, 0, 0);
        }
    }
    // deferred row-sum reduce: combine the 4 lane-groups
    ll += __shfl_xor(ll, 16);
    ll += __shfl_xor(ll, 32);
    // epilogue
#pragma unroll
    for (int j = 0; j < 4; j++) {
        const float lr = __shfl(ll, r0 + j);
        const size_t row = (size_t)(bb * T_SEQ + q0 + w * 16 + r0 + j);
        if (lr > 0.f) {
            const float rinv = 1.0f / lr;
#pragma unroll
            for (int ni = 0; ni < 4; ni++)
                Ob[row * C_DIM + h * DH + ni * 16 + qq] = f2bf(o[ni][j] * rinv);
        } else {
            // fully-masked row (row 1023): reference softmax is uniform -> mean of V
#pragma unroll
            for (int ni = 0; ni < 4; ni++)
                Ob[row * C_DIM + h * DH + ni * 16 + qq] = f2bf(Vmean[bh * DH + ni * 16 + qq]);
        }
    }
}

extern "C" void kernel_launch(void* const* d_in, const int* in_sizes, int n_in,
                              void* d_out, int out_size, void* d_ws, size_t ws_size,
                              hipStream_t stream) {
    const float* x  = (const float*)d_in[0];
    const float* Wq = (const float*)d_in[1];
    const float* bq = (const float*)d_in[2];
    const float* Wk = (const float*)d_in[3];
    const float* bk = (const float*)d_in[4];
    const float* Wv = (const float*)d_in[5];
    const float* bv = (const float*)d_in[6];
    const float* Wo = (const float*)d_in[7];
    const float* bo = (const float*)d_in[8];
    float* out = (float*)d_out;

    char* ws = (char*)d_ws;
    uint16_t* xb    = (uint16_t*)(ws);               // 8 MB
    uint16_t* wqkvt = (uint16_t*)(ws + (8u  << 20)); // 8 MB: Wq,Wk,Wv,Wo transposed bf16
    float*    vmean = (float*)   (ws + (12u << 20)); // 16 KB (inside wqkvt pad)
    uint16_t* qb    = (uint16_t*)(ws + (16u << 20)); // 8 MB
    uint16_t* kb    = (uint16_t*)(ws + (24u << 20)); // 8 MB
    uint16_t* vt    = (uint16_t*)(ws + (32u << 20)); // 8 MB
    uint16_t* wot   = wqkvt + (3u << 20);
    uint16_t* ab    = qb;  // attn out aliases qb: blocks read their own q rows before writing them

    k_cast<<<2048, 256, 0, stream>>>(x, xb, (4096 * 1024) / 4);
    k_transpose4<<<dim3(32, 32, 4), dim3(32, 8), 0, stream>>>(Wq, Wk, Wv, Wo, wqkvt);

    k_gemm_qkv<<<dim3(32, 24), 256, 0, stream>>>(xb, wqkvt, bq, bk, bv, qb, kb, vt);
    k_vmean<<<64, 256, 0, stream>>>(vt, vmean);
    k_attn<<<1024, 256, 0, stream>>>(qb, kb, vt, vmean, ab);
    k_gemm_o<<<dim3(32, 8), 256, 0, stream>>>(ab, wot, bo, out);
}

// Round 6
// 145.161 us; speedup vs baseline: 1.0723x; 1.0723x over previous
//
#include <hip/hip_runtime.h>
#include <hip/hip_bf16.h>
#include <stdint.h>

#define T_SEQ 1024
#define C_DIM 1024
#define NH 16
#define DH 64

typedef __attribute__((ext_vector_type(8))) __bf16 bf16x8;
typedef __attribute__((ext_vector_type(8))) uint16_t u16x8;
typedef __attribute__((ext_vector_type(4))) float f32x4;

__device__ __forceinline__ uint16_t f2bf(float f) {
    union { float f; uint32_t u; } v; v.f = f;
    uint32_t u = v.u;
    return (uint16_t)((u + 0x7FFFu + ((u >> 16) & 1u)) >> 16);
}
__device__ __forceinline__ float bf2f(uint16_t b) {
    union { uint32_t u; float f; } v; v.u = ((uint32_t)b) << 16; return v.f;
}

// ---------- cast x f32 -> bf16 (vectorized) ----------
__global__ void k_cast(const float* __restrict__ in, uint16_t* __restrict__ out, int n4) {
    int i = blockIdx.x * blockDim.x + threadIdx.x;
    int st = gridDim.x * blockDim.x;
    for (; i < n4; i += st) {
        float4 v = reinterpret_cast<const float4*>(in)[i];
        ushort4 o;
        o.x = f2bf(v.x); o.y = f2bf(v.y); o.z = f2bf(v.z); o.w = f2bf(v.w);
        reinterpret_cast<ushort4*>(out)[i] = o;
    }
}

// ---------- fused transpose+cast of all 4 weights: W[k][n] f32 -> Wt[n][k] bf16 ----------
__global__ void k_transpose4(const float* __restrict__ W0, const float* __restrict__ W1,
                             const float* __restrict__ W2, const float* __restrict__ W3,
                             uint16_t* __restrict__ out) {
    __shared__ float tile[32][33];
    const float* in = (blockIdx.z == 0) ? W0 : (blockIdx.z == 1) ? W1 : (blockIdx.z == 2) ? W2 : W3;
    uint16_t* o = out + ((size_t)blockIdx.z << 20);
    int bx = blockIdx.x * 32;
    int by = blockIdx.y * 32;
    int tx = threadIdx.x, ty = threadIdx.y;
#pragma unroll
    for (int i = 0; i < 4; i++)
        tile[ty + i * 8][tx] = in[(size_t)(by + ty + i * 8) * C_DIM + bx + tx];
    __syncthreads();
#pragma unroll
    for (int i = 0; i < 4; i++)
        o[(size_t)(bx + ty + i * 8) * C_DIM + by + tx] = f2bf(tile[tx][ty + i * 8]);
}

// ---------- V column mean (uniform-softmax fallback for fully-masked rows) ----------
__global__ void k_vmean(const uint16_t* __restrict__ Vt, float* __restrict__ Vmean) {
    const int bh = blockIdx.x;
    const int tid = threadIdx.x;
    const int d = tid >> 2, part = tid & 3;
    const uint16_t* src = Vt + ((size_t)bh * DH + d) * T_SEQ + part * 256;
    float s = 0.f;
#pragma unroll
    for (int i = 0; i < 32; i++) {
        u16x8 v = *reinterpret_cast<const u16x8*>(src + i * 8);
#pragma unroll
        for (int j = 0; j < 8; j++) s += bf2f(v[j]);
    }
    s += __shfl_xor(s, 1);
    s += __shfl_xor(s, 2);
    if (part == 0) Vmean[bh * DH + d] = s * (1.0f / 1024.0f);
}

// ---------- GEMM staging (R4 structure): one 128x32 A tile + 128x32 B tile ----------
__device__ __forceinline__ void stage_g(const uint16_t* A, const uint16_t* Bt, int bm, int bn,
                                        int kt, char* la, char* lb, int tid) {
    const int w = tid >> 6, srow = tid >> 2, scol = (tid & 3) * 8;
#pragma unroll
    for (int p = 0; p < 2; p++) {
        const uint16_t* ga = A + (size_t)(bm + p * 64 + srow) * C_DIM + kt + scol;
        const uint16_t* gb = Bt + (size_t)(bn + p * 64 + srow) * C_DIM + kt + scol;
        __builtin_amdgcn_global_load_lds(
            (const __attribute__((address_space(1))) void*)ga,
            (__attribute__((address_space(3))) void*)(la + p * 4096 + w * 1024), 16, 0, 0);
        __builtin_amdgcn_global_load_lds(
            (const __attribute__((address_space(1))) void*)gb,
            (__attribute__((address_space(3))) void*)(lb + p * 4096 + w * 1024), 16, 0, 0);
    }
}

// ---------- fused QKV GEMM (R4 single-buffer 2-barrier) ----------
__global__ __launch_bounds__(256) void k_gemm_qkv(const uint16_t* __restrict__ A,
                                                  const uint16_t* __restrict__ Bt,
                                                  const float* __restrict__ bq,
                                                  const float* __restrict__ bk,
                                                  const float* __restrict__ bv,
                                                  uint16_t* __restrict__ qb,
                                                  uint16_t* __restrict__ kb,
                                                  uint16_t* __restrict__ vt) {
    __shared__ uint16_t lA[128 * 32];
    __shared__ uint16_t lB[128 * 32];
    const int bm = blockIdx.x * 128;
    const int bn = blockIdx.y * 128;
    const int tid = threadIdx.x;
    const int lane = tid & 63;
    const int w = tid >> 6;
    const int wm = (w >> 1) * 64;
    const int wn = (w & 1) * 64;
    const int ko = (lane >> 4) * 8;
    const int rr = lane & 15;

    f32x4 acc[4][4] = {};

    for (int kt = 0; kt < C_DIM; kt += 32) {
        stage_g(A, Bt, bm, bn, kt, (char*)lA, (char*)lB, tid);
        __syncthreads();
        bf16x8 af[4], bfr[4];
#pragma unroll
        for (int i = 0; i < 4; i++) {
            af[i]  = *reinterpret_cast<const bf16x8*>(&lA[(wm + i * 16 + rr) * 32 + ko]);
            bfr[i] = *reinterpret_cast<const bf16x8*>(&lB[(wn + i * 16 + rr) * 32 + ko]);
        }
#pragma unroll
        for (int mi = 0; mi < 4; mi++)
#pragma unroll
            for (int ni = 0; ni < 4; ni++)
                acc[mi][ni] = __builtin_amdgcn_mfma_f32_16x16x32_bf16(af[mi], bfr[ni], acc[mi][ni], 0, 0, 0);
        __syncthreads();
    }

    const float* bias; uint16_t* outp; int coff, vmode;
    if (bn < 1024)      { bias = bq; outp = qb; coff = 0;    vmode = 0; }
    else if (bn < 2048) { bias = bk; outp = kb; coff = 1024; vmode = 0; }
    else                { bias = bv; outp = vt; coff = 2048; vmode = 1; }

    const int r0 = (lane >> 4) * 4;
    const int cc = lane & 15;
#pragma unroll
    for (int ni = 0; ni < 4; ni++) {
        const int colg = bn + wn + ni * 16 + cc;
        const int col = colg - coff;
        const float bvv = bias[col];
#pragma unroll
        for (int mi = 0; mi < 4; mi++) {
#pragma unroll
            for (int jj = 0; jj < 4; jj++) {
                const int row = bm + wm + mi * 16 + r0 + jj;
                float v = acc[mi][ni][jj] + bvv;
                if (vmode == 0) {
                    outp[(size_t)row * C_DIM + col] = f2bf(v);
                } else {
                    const int b = row >> 10, t2 = row & 1023;
                    const int h = col >> 6, d = col & 63;
                    outp[((size_t)((b * NH + h) * DH + d) << 10) + t2] = f2bf(v);
                }
            }
        }
    }
}

// ---------- output-proj GEMM (R4 structure): f32 out ----------
__global__ __launch_bounds__(256) void k_gemm_o(const uint16_t* __restrict__ A,
                                                const uint16_t* __restrict__ Bt,
                                                const float* __restrict__ bias,
                                                float* __restrict__ Out) {
    __shared__ uint16_t lA[128 * 32];
    __shared__ uint16_t lB[128 * 32];
    const int bm = blockIdx.x * 128;
    const int bn = blockIdx.y * 128;
    const int tid = threadIdx.x;
    const int lane = tid & 63;
    const int w = tid >> 6;
    const int wm = (w >> 1) * 64;
    const int wn = (w & 1) * 64;
    const int ko = (lane >> 4) * 8;
    const int rr = lane & 15;

    f32x4 acc[4][4] = {};

    for (int kt = 0; kt < C_DIM; kt += 32) {
        stage_g(A, Bt, bm, bn, kt, (char*)lA, (char*)lB, tid);
        __syncthreads();
        bf16x8 af[4], bfr[4];
#pragma unroll
        for (int i = 0; i < 4; i++) {
            af[i]  = *reinterpret_cast<const bf16x8*>(&lA[(wm + i * 16 + rr) * 32 + ko]);
            bfr[i] = *reinterpret_cast<const bf16x8*>(&lB[(wn + i * 16 + rr) * 32 + ko]);
        }
#pragma unroll
        for (int mi = 0; mi < 4; mi++)
#pragma unroll
            for (int ni = 0; ni < 4; ni++)
                acc[mi][ni] = __builtin_amdgcn_mfma_f32_16x16x32_bf16(af[mi], bfr[ni], acc[mi][ni], 0, 0, 0);
        __syncthreads();
    }

    const int r0 = (lane >> 4) * 4;
    const int cc = lane & 15;
#pragma unroll
    for (int ni = 0; ni < 4; ni++) {
        const int col = bn + wn + ni * 16 + cc;
        const float bvv = bias[col];
#pragma unroll
        for (int mi = 0; mi < 4; mi++)
#pragma unroll
            for (int jj = 0; jj < 4; jj++) {
                const int row = bm + wm + mi * 16 + r0 + jj;
                Out[(size_t)row * C_DIM + col] = acc[mi][ni][jj] + bvv;
            }
    }
}

// ---------- flash attention: barrier-free, wave-independent q-tiles ----------
// Wave = one 16-row q-tile over its unmasked KV tiles; m=0 softmax (tiles independent);
// K and V direct global->reg; P bounced through wave-private double-buffered LDS.
// Block (bh, g) carries qt {2g, 2g+1, 62-2g, 63-2g} -> exactly 34 tiles per block.
__global__ __launch_bounds__(256, 4) void k_attn(const uint16_t* __restrict__ Q,
                                                 const uint16_t* __restrict__ Kb,
                                                 const uint16_t* __restrict__ Vt,
                                                 const float* __restrict__ Vmean,
                                                 uint16_t* __restrict__ Ob) {
    __shared__ char smem[4 * 4608];   // per-wave P dbuf: 2 x (16 x 72 x 2B)
    const int tid = threadIdx.x;
    const int lane = tid & 63;
    const int w = tid >> 6;
    uint16_t* lpb = reinterpret_cast<uint16_t*>(smem) + w * 2304;

    // XCD swizzle (bijective, 1024%8==0): one bh's 16 blocks stay on one XCD
    const int id = blockIdx.x;
    const int sw = (id & 7) * 128 + (id >> 3);
    const int bh = sw >> 4;
    const int g  = sw & 15;
    const int qt = (w == 0) ? 2 * g : (w == 1) ? 2 * g + 1 : (w == 2) ? 62 - 2 * g : 63 - 2 * g;
    const int q0 = qt * 16;
    const int bb = bh >> 4, h = bh & 15;
    const int qq = lane & 15;
    const int gg = lane >> 4;
    const int ko = gg * 8;
    const int r0 = gg * 4;
    const int qg = q0 + qq;

    const uint16_t* qp = Q + (size_t)(bb * T_SEQ + qg) * C_DIM + h * DH + ko;
    bf16x8 bq0 = *reinterpret_cast<const bf16x8*>(qp);
    bf16x8 bq1 = *reinterpret_cast<const bf16x8*>(qp + 32);

    const uint16_t* kbase = Kb + (size_t)bb * T_SEQ * C_DIM + h * DH;
    const uint16_t* vbase = Vt + (size_t)bh * DH * T_SEQ;

    f32x4 o[4] = {};
    float ll = 0.f;
    const float zs = 0.125f * 1.44269504088896f;

    // skip tiles fully below diagonal (exact zeros); t0 = qt>>2
    const int t0 = qt >> 2;
    for (int t = t0; t < 16; t++) {
        const int s0 = t * 64;
        uint16_t* lp = lpb + (t & 1) * 1152;

        bf16x8 kf[4][2];
#pragma unroll
        for (int hf = 0; hf < 4; hf++) {
            const uint16_t* kp = kbase + (size_t)(s0 + hf * 16 + qq) * C_DIM + ko;
            kf[hf][0] = *reinterpret_cast<const bf16x8*>(kp);
            kf[hf][1] = *reinterpret_cast<const bf16x8*>(kp + 32);
        }
        bf16x8 vf[4][2];
#pragma unroll
        for (int ni = 0; ni < 4; ni++) {
            const uint16_t* vp = vbase + (size_t)(ni * 16 + qq) * T_SEQ + s0 + ko;
            vf[ni][0] = *reinterpret_cast<const bf16x8*>(vp);
            vf[ni][1] = *reinterpret_cast<const bf16x8*>(vp + 32);
        }

        f32x4 sc[4];
#pragma unroll
        for (int hf = 0; hf < 4; hf++) {
            f32x4 tt = {};
            tt = __builtin_amdgcn_mfma_f32_16x16x32_bf16(kf[hf][0], bq0, tt, 0, 0, 0);
            tt = __builtin_amdgcn_mfma_f32_16x16x32_bf16(kf[hf][1], bq1, tt, 0, 0, 0);
            sc[hf] = tt;   // sc[hf][j] = S[k=s0+hf*16+r0+j][q=qg]
        }
        // m=0 softmax: P = exp2(z); masked (k<=qg) -> z-1e9 -> P = 0 exactly
#pragma unroll
        for (int hf = 0; hf < 4; hf++)
#pragma unroll
            for (int j = 0; j < 4; j++) {
                const int k = s0 + hf * 16 + r0 + j;
                const float z = sc[hf][j] * zs + ((k <= qg) ? -1e9f : 0.0f);
                const float p = __builtin_amdgcn_exp2f(z);
                sc[hf][j] = p;
                ll += p;
            }
        // pack P -> wave-private LDS (lp[q][k], stride 72)
        uint32_t* lp32 = reinterpret_cast<uint32_t*>(lp);
#pragma unroll
        for (int hf = 0; hf < 4; hf++)
#pragma unroll
            for (int jp = 0; jp < 2; jp++) {
                union { __hip_bfloat162 h2; uint32_t u; } cv;
                cv.h2 = __float22bfloat162_rn(make_float2(sc[hf][2 * jp], sc[hf][2 * jp + 1]));
                lp32[qq * 36 + hf * 8 + (r0 >> 1) + jp] = cv.u;
            }
        bf16x8 pa0 = *reinterpret_cast<const bf16x8*>(&lp[qq * 72 + ko]);
        bf16x8 pa1 = *reinterpret_cast<const bf16x8*>(&lp[qq * 72 + 32 + ko]);
#pragma unroll
        for (int ni = 0; ni < 4; ni++) {
            o[ni] = __builtin_amdgcn_mfma_f32_16x16x32_bf16(pa0, vf[ni][0], o[ni], 0, 0, 0);
            o[ni] = __builtin_amdgcn_mfma_f32_16x16x32_bf16(pa1, vf[ni][1], o[ni], 0, 0, 0);
        }
    }
    // deferred row-sum reduce across the 4 lane-groups
    ll += __shfl_xor(ll, 16);
    ll += __shfl_xor(ll, 32);
    // epilogue: O[row=q0+r0+j][d=ni*16+qq]
#pragma unroll
    for (int j = 0; j < 4; j++) {
        const float lr = __shfl(ll, r0 + j);
        const size_t row = (size_t)(bb * T_SEQ + q0 + r0 + j);
        if (lr > 0.f) {
            const float rinv = 1.0f / lr;
#pragma unroll
            for (int ni = 0; ni < 4; ni++)
                Ob[row * C_DIM + h * DH + ni * 16 + qq] = f2bf(o[ni][j] * rinv);
        } else {
            // fully-masked row (row 1023): reference softmax uniform -> mean of V
#pragma unroll
            for (int ni = 0; ni < 4; ni++)
                Ob[row * C_DIM + h * DH + ni * 16 + qq] = f2bf(Vmean[bh * DH + ni * 16 + qq]);
        }
    }
}

extern "C" void kernel_launch(void* const* d_in, const int* in_sizes, int n_in,
                              void* d_out, int out_size, void* d_ws, size_t ws_size,
                              hipStream_t stream) {
    const float* x  = (const float*)d_in[0];
    const float* Wq = (const float*)d_in[1];
    const float* bq = (const float*)d_in[2];
    const float* Wk = (const float*)d_in[3];
    const float* bk = (const float*)d_in[4];
    const float* Wv = (const float*)d_in[5];
    const float* bv = (const float*)d_in[6];
    const float* Wo = (const float*)d_in[7];
    const float* bo = (const float*)d_in[8];
    float* out = (float*)d_out;

    char* ws = (char*)d_ws;
    uint16_t* xb    = (uint16_t*)(ws);               // 8 MB
    uint16_t* wqkvt = (uint16_t*)(ws + (8u  << 20)); // 8 MB: Wq,Wk,Wv,Wo transposed bf16
    float*    vmean = (float*)   (ws + (12u << 20)); // 16 KB (hole in ws map)
    uint16_t* qb    = (uint16_t*)(ws + (16u << 20)); // 8 MB
    uint16_t* kb    = (uint16_t*)(ws + (24u << 20)); // 8 MB
    uint16_t* vt    = (uint16_t*)(ws + (32u << 20)); // 8 MB
    uint16_t* wot   = wqkvt + (3u << 20);
    uint16_t* ab    = qb;  // attn out aliases qb: each wave reads its own q rows before writing them

    k_cast<<<2048, 256, 0, stream>>>(x, xb, (4096 * 1024) / 4);
    k_transpose4<<<dim3(32, 32, 4), dim3(32, 8), 0, stream>>>(Wq, Wk, Wv, Wo, wqkvt);

    k_gemm_qkv<<<dim3(32, 24), 256, 0, stream>>>(xb, wqkvt, bq, bk, bv, qb, kb, vt);
    k_vmean<<<64, 256, 0, stream>>>(vt, vmean);
    k_attn<<<1024, 256, 0, stream>>>(qb, kb, vt, vmean, ab);
    k_gemm_o<<<dim3(32, 8), 256, 0, stream>>>(ab, wot, bo, out);
}